// Round 7
// baseline (1630.788 us; speedup 1.0000x reference)
//
#include <hip/hip_runtime.h>
#include <stdint.h>

#define B_ 4
#define H_ 16
#define S_ 2048
#define D_ 64
#define QBLK 16
#define NTH 512
#define KSLAB 256
#define NWIN 8                        /* KSLAB/32 */

typedef __attribute__((ext_vector_type(8))) short short8;
typedef __attribute__((ext_vector_type(4))) float float4v;
typedef __attribute__((ext_vector_type(4))) unsigned int uint4v;
typedef __attribute__((ext_vector_type(2))) unsigned int uint2v;

static __device__ __forceinline__ short f2bf(float f) {
  uint32_t u = __builtin_bit_cast(uint32_t, f);
  u = (u + 0x7FFFu + ((u >> 16) & 1u)) >> 16;   // RNE
  return (short)u;
}
static __device__ __forceinline__ float bf2f(short s) {
  uint32_t u = ((uint32_t)(uint16_t)s) << 16;
  return __builtin_bit_cast(float, u);
}
static __device__ __forceinline__ uint32_t packbf(float lo, float hi) {
  return ((uint32_t)(uint16_t)f2bf(hi) << 16) | (uint16_t)f2bf(lo);
}
static __device__ __forceinline__ uint32_t nz4(uint32_t d) {
  uint32_t x = (d & 0x7F7F7F7Fu) + 0x7F7F7F7Fu;
  x = (x | d) & 0x80808080u;
  return x >> 7;
}
static __device__ __forceinline__ uint32_t nib(uint32_t d) {
  return ((nz4(d) * 0x01020408u) >> 24) & 0xFu;
}

#define LSUM_OFF   ((size_t)64)
#define LSUM_BYTES ((size_t)B_ * H_ * S_ * 4)          /* 512 KB */
#define KBF_OFF    (LSUM_OFF + LSUM_BYTES)
#define KBF_BYTES  ((size_t)B_ * H_ * S_ * D_ * 2)     /* 16 MB */
#define VT_OFF     (KBF_OFF + KBF_BYTES)
#define VT_BYTES   ((size_t)B_ * H_ * S_ * D_ * 2)     /* 16 MB */

__global__ void detect_mask_dtype(const uint8_t* __restrict__ m, uint32_t* flag) {
  uint32_t a = 0, b = 0;
  for (int i = threadIdx.x; i < 65536; i += 256) {
    uint8_t x = m[i];
    if (i & 3) a |= x; else b |= x;
  }
  uint32_t bits = (a ? 1u : 0u) | (b ? 2u : 0u);
  if (bits) atomicOr(flag, bits);
}

__global__ __launch_bounds__(256) void prep_k(const float* __restrict__ K,
                                              short* __restrict__ Kbf) {
  size_t base = ((size_t)blockIdx.x * 256 + threadIdx.x) * 8;
  float4v a = __builtin_nontemporal_load((const float4v*)(K + base));
  float4v b = __builtin_nontemporal_load((const float4v*)(K + base + 4));
  short8 o;
  o[0]=f2bf(a.x); o[1]=f2bf(a.y); o[2]=f2bf(a.z); o[3]=f2bf(a.w);
  o[4]=f2bf(b.x); o[5]=f2bf(b.y); o[6]=f2bf(b.z); o[7]=f2bf(b.w);
  *(short8*)(Kbf + base) = o;
}

__global__ __launch_bounds__(256) void prep_vt(const float* __restrict__ V,
                                               short* __restrict__ VT) {
  __shared__ short tile[64][72];
  int bh = blockIdx.x >> 5, k0 = (blockIdx.x & 31) * 64;
  const float* src = V + ((size_t)bh * S_ + k0) * D_;
  int t = threadIdx.x;
  int r = t >> 2, c0 = (t & 3) * 16;
#pragma unroll
  for (int j = 0; j < 4; ++j) {
    float4v f = __builtin_nontemporal_load((const float4v*)(src + (size_t)r * D_ + c0 + j * 4));
    tile[r][c0 + j*4 + 0] = f2bf(f.x);
    tile[r][c0 + j*4 + 1] = f2bf(f.y);
    tile[r][c0 + j*4 + 2] = f2bf(f.z);
    tile[r][c0 + j*4 + 3] = f2bf(f.w);
  }
  __syncthreads();
  int d = t >> 2, ks0 = (t & 3) * 16;
  short* dst = VT + (size_t)bh * D_ * S_ + (size_t)d * S_ + k0 + ks0;
#pragma unroll
  for (int half = 0; half < 2; ++half) {
    short8 o;
#pragma unroll
    for (int i = 0; i < 8; ++i) o[i] = tile[ks0 + half * 8 + i][d];
    *(short8*)(dst + half * 8) = o;
  }
}

// ---------------- Pass 1: QK^T -> exp -> E(bf16, row upper half) + rowsums ----
template <int PREP>
__global__ __launch_bounds__(NTH, 4) void k_scores(
    const float* __restrict__ Q, const float* __restrict__ K,
    const float* __restrict__ scale_p, const uint8_t* __restrict__ M,
    const uint32_t* __restrict__ flag, const short* __restrict__ Kbf,
    float* __restrict__ lsumG, float* __restrict__ outA)
{
  __shared__ uint32_t mbits[QBLK * 65];
  __shared__ float lsum_s[QBLK];

  const int bx  = (blockIdx.x & 7) * 1024 + (blockIdx.x >> 3);
  const int bh  = bx >> 7;
  const int q0  = (bx & 127) * QBLK;
  const int tid = threadIdx.x;
  const int w   = tid >> 6, lane = tid & 63, g = lane >> 4, c = lane & 15;
  const int kslab0 = w * KSLAB;
  const float scale = scale_p[0];
  const uint32_t fl = flag[0];

  // mask bitmap prologue
  {
    const int row = tid >> 5;
    const int w0  = (tid & 31) * 2;
    if (fl == 3u) {
      const uint8_t* mrow = M + ((size_t)bh * S_ + q0 + row) * (size_t)S_ + w0 * 32;
#pragma unroll
      for (int j = 0; j < 2; ++j) {
        uint4v a = __builtin_nontemporal_load((const uint4v*)(mrow + j * 32));
        uint4v b = __builtin_nontemporal_load((const uint4v*)(mrow + j * 32 + 16));
        uint32_t bits = nib(a.x) | (nib(a.y) << 4) | (nib(a.z) << 8)  | (nib(a.w) << 12)
                      | (nib(b.x) << 16) | (nib(b.y) << 20) | (nib(b.z) << 24) | (nib(b.w) << 28);
        mbits[row * 65 + w0 + j] = bits;
      }
    } else {
      const uint32_t* mrow = (const uint32_t*)M + ((size_t)bh * S_ + q0 + row) * (size_t)S_ + w0 * 32;
#pragma unroll
      for (int j = 0; j < 2; ++j) {
        uint32_t bits = 0;
#pragma unroll
        for (int u = 0; u < 8; ++u) {
          uint4v wv = __builtin_nontemporal_load((const uint4v*)(mrow + j * 32 + u * 4));
          uint32_t nzb = (wv.x ? 1u : 0u) | (wv.y ? 2u : 0u) | (wv.z ? 4u : 0u) | (wv.w ? 8u : 0u);
          bits |= nzb << (u * 4);
        }
        mbits[row * 65 + w0 + j] = bits;
      }
    }
    if (tid < QBLK) lsum_s[tid] = 0.0f;
  }
  __syncthreads();

  // Q as B-frag: lane holds Q[q0+c][.]
  short8 qB[2];
#pragma unroll
  for (int h = 0; h < 2; ++h) {
    const float* qr = Q + ((size_t)(bh * S_ + q0 + c)) * D_ + h * 32 + g * 8;
    float4v a = *(const float4v*)qr;
    float4v b = *(const float4v*)(qr + 4);
    short8 f;
    f[0]=f2bf(a.x); f[1]=f2bf(a.y); f[2]=f2bf(a.z); f[3]=f2bf(a.w);
    f[4]=f2bf(b.x); f[5]=f2bf(b.y); f[6]=f2bf(b.z); f[7]=f2bf(b.w);
    qB[h] = f;
  }

  const uint32_t* mrowp = &mbits[c * 65 + (kslab0 >> 5)];
  const short* Kbp = Kbf + (size_t)bh * S_ * D_;
  const float* Kfp = K + (size_t)bh * S_ * D_;
  // E row for this lane: upper 4KB half of outA row (q0+c)
  char* erow = (char*)outA + ((size_t)(bh * S_ + q0 + c) * S_) * 4 + (size_t)S_ * 2;

  float rsv = 0.0f;
#pragma unroll
  for (int win = 0; win < NWIN; ++win) {
    const int kwin = kslab0 + win * 32;
    short8 a0, a1, a2, a3;
    if (PREP) {
      const short* kr = Kbp + (size_t)(kwin + c) * D_ + g * 8;
      a0 = *(const short8*)kr;
      a1 = *(const short8*)(kr + 32);
      const short* kr1 = kr + 16 * D_;
      a2 = *(const short8*)kr1;
      a3 = *(const short8*)(kr1 + 32);
    } else {
      const float* kr = Kfp + (size_t)(kwin + c) * D_ + g * 8;
      const float* kr1 = kr + 16 * D_;
#pragma unroll
      for (int e = 0; e < 8; ++e) {
        a0[e] = f2bf(kr[e]);  a1[e] = f2bf(kr[32 + e]);
        a2[e] = f2bf(kr1[e]); a3[e] = f2bf(kr1[32 + e]);
      }
    }
    float4v acc0 = (float4v){0.f,0.f,0.f,0.f};
    float4v acc1 = (float4v){0.f,0.f,0.f,0.f};
    acc0 = __builtin_amdgcn_mfma_f32_16x16x32_bf16(a0, qB[0], acc0, 0, 0, 0);
    acc0 = __builtin_amdgcn_mfma_f32_16x16x32_bf16(a1, qB[1], acc0, 0, 0, 0);
    acc1 = __builtin_amdgcn_mfma_f32_16x16x32_bf16(a2, qB[0], acc1, 0, 0, 0);
    acc1 = __builtin_amdgcn_mfma_f32_16x16x32_bf16(a3, qB[1], acc1, 0, 0, 0);

    const uint32_t mw = mrowp[win];
    float e0[4], e1[4];
#pragma unroll
    for (int r = 0; r < 4; ++r) {
      e0[r] = ((mw >> (4 * g + r)) & 1u)        ? 1.0f : __expf(acc0[r] * scale);
      e1[r] = ((mw >> (16 + 4 * g + r)) & 1u)   ? 1.0f : __expf(acc1[r] * scale);
      rsv += e0[r] + e1[r];
    }
    uint2v lo, hi2;
    lo.x  = packbf(e0[0], e0[1]);  lo.y  = packbf(e0[2], e0[3]);
    hi2.x = packbf(e1[0], e1[1]);  hi2.y = packbf(e1[2], e1[3]);
    *(uint2v*)(erow + (size_t)(kwin + 4 * g) * 2)      = lo;   // k = kwin+4g..+3
    *(uint2v*)(erow + (size_t)(kwin + 16 + 4 * g) * 2) = hi2;  // k = kwin+16+4g..+3
  }
  rsv += __shfl_xor(rsv, 16);
  rsv += __shfl_xor(rsv, 32);
  if (lane < 16) atomicAdd(&lsum_s[lane], rsv);
  __syncthreads();
  if (tid < QBLK) lsumG[(size_t)bh * S_ + q0 + tid] = lsum_s[tid];
}

// ---------------- Pass 2: PV + normalized attention overwrite ----------------
template <int PREP>
__global__ __launch_bounds__(NTH, 2) void k_pv(
    const float* __restrict__ V, const short* __restrict__ VT,
    const float* __restrict__ lsumG, float* __restrict__ outC,
    float* __restrict__ outA)
{
  __shared__ float linv_s[QBLK];
  __shared__ float cbuf[QBLK * 65];

  const int bx  = (blockIdx.x & 7) * 1024 + (blockIdx.x >> 3);
  const int bh  = bx >> 7;
  const int q0  = (bx & 127) * QBLK;
  const int tid = threadIdx.x;
  const int w   = tid >> 6, lane = tid & 63, g = lane >> 4, c = lane & 15;
  const int kslab0 = w * KSLAB;

  if (tid < QBLK) linv_s[tid] = 1.0f / lsumG[(size_t)bh * S_ + q0 + tid];
  for (int i = tid; i < QBLK * 65; i += NTH) cbuf[i] = 0.0f;
  __syncthreads();

  const short* ebase = (const short*)((char*)outA +
      ((size_t)(bh * S_ + q0 + c) * S_) * 4 + (size_t)S_ * 2);
  const short* VTp = VT + (size_t)bh * D_ * S_;
  const float* Vfp = V + (size_t)bh * S_ * D_;

  float4v cacc[4];
#pragma unroll
  for (int nd = 0; nd < 4; ++nd) cacc[nd] = (float4v){0.f, 0.f, 0.f, 0.f};

#pragma unroll
  for (int win = 0; win < NWIN; ++win) {
    const int kwin = kslab0 + win * 32;
    const short8 eA = *(const short8*)(ebase + kwin + g * 8);  // E[q=c][kwin+g*8..+7]
#pragma unroll
    for (int nd = 0; nd < 4; ++nd) {
      short8 vB;
      if (PREP) {
        vB = *(const short8*)&VTp[(size_t)(nd * 16 + c) * S_ + kwin + g * 8];
      } else {
        const float* vc = Vfp + (size_t)(kwin + g * 8) * D_ + nd * 16 + c;
#pragma unroll
        for (int e = 0; e < 8; ++e) vB[e] = f2bf(vc[(size_t)e * D_]);
      }
      cacc[nd] = __builtin_amdgcn_mfma_f32_16x16x32_bf16(eA, vB, cacc[nd], 0, 0, 0);
    }
  }
  // ctx partial reduce: D row q = 4g+r, col d = nd*16+c
#pragma unroll
  for (int nd = 0; nd < 4; ++nd)
#pragma unroll
    for (int r = 0; r < 4; ++r)
      atomicAdd(&cbuf[(4 * g + r) * 65 + nd * 16 + c], cacc[nd][r]);
  __syncthreads();

  // context write
  if (tid < QBLK * D_ / 4) {
    const int row = tid >> 4, d0 = (tid & 15) * 4;
    const float inv = linv_s[row];
    float4v cv;
    cv.x = cbuf[row * 65 + d0 + 0] * inv;
    cv.y = cbuf[row * 65 + d0 + 1] * inv;
    cv.z = cbuf[row * 65 + d0 + 2] * inv;
    cv.w = cbuf[row * 65 + d0 + 3] * inv;
    *(float4v*)&outC[((size_t)(bh * S_ + q0 + row)) * D_ + d0] = cv;
  }

  // stage ALL E for this block in regs (4 bf16/thread/row), then overwrite rows
  uint2v ev[QBLK];
#pragma unroll
  for (int it = 0; it < QBLK; ++it) {
    const short* er = (const short*)((char*)outA +
        ((size_t)(bh * S_ + q0 + it) * S_) * 4 + (size_t)S_ * 2);
    ev[it] = *(const uint2v*)(er + tid * 4);
  }
  __syncthreads();   // all E reads complete before any overwrite

  float* arow0 = outA + ((size_t)(bh * S_ + q0)) * S_ + tid * 4;
#pragma unroll
  for (int it = 0; it < QBLK; ++it) {
    const float inv = linv_s[it];
    float4v av;
    av.x = bf2f((short)(ev[it].x & 0xffff)) * inv;
    av.y = bf2f((short)(ev[it].x >> 16))    * inv;
    av.z = bf2f((short)(ev[it].y & 0xffff)) * inv;
    av.w = bf2f((short)(ev[it].y >> 16))    * inv;
    *(float4v*)(arow0 + (size_t)it * S_) = av;
  }
}

extern "C" void kernel_launch(void* const* d_in, const int* in_sizes, int n_in,
                              void* d_out, int out_size, void* d_ws, size_t ws_size,
                              hipStream_t stream) {
  const float*   Q     = (const float*)d_in[0];
  const float*   K     = (const float*)d_in[1];
  const float*   V     = (const float*)d_in[2];
  const float*   scale = (const float*)d_in[3];
  const uint8_t* M     = (const uint8_t*)d_in[4];
  uint32_t* flag  = (uint32_t*)d_ws;
  float*    lsumG = (float*)((char*)d_ws + LSUM_OFF);
  short*    Kbf   = (short*)((char*)d_ws + KBF_OFF);
  short*    VT    = (short*)((char*)d_ws + VT_OFF);
  float* outC = (float*)d_out;
  float* outA = outC + (size_t)B_ * H_ * S_ * D_;

  hipMemsetAsync(flag, 0, 4, stream);
  detect_mask_dtype<<<dim3(1), dim3(256), 0, stream>>>(M, flag);

  const bool prep = ws_size >= VT_OFF + VT_BYTES;
  const int grid = B_ * H_ * (S_ / QBLK);
  if (prep) {
    prep_k<<<dim3((B_ * H_ * S_ * D_) / (256 * 8)), dim3(256), 0, stream>>>(K, Kbf);
    prep_vt<<<dim3(B_ * H_ * (S_ / 64)), dim3(256), 0, stream>>>(V, VT);
    k_scores<1><<<dim3(grid), dim3(NTH), 0, stream>>>(Q, K, scale, M, flag, Kbf, lsumG, outA);
    k_pv<1><<<dim3(grid), dim3(NTH), 0, stream>>>(V, VT, lsumG, outC, outA);
  } else {
    k_scores<0><<<dim3(grid), dim3(NTH), 0, stream>>>(Q, K, scale, M, flag, Kbf, lsumG, outA);
    k_pv<0><<<dim3(grid), dim3(NTH), 0, stream>>>(V, VT, lsumG, outC, outA);
  }
}

// Round 8
// 1154.356 us; speedup vs baseline: 1.4127x; 1.4127x over previous
//
#include <hip/hip_runtime.h>
#include <stdint.h>

#define B_ 4
#define H_ 16
#define S_ 2048
#define D_ 64
#define QBLK 16
#define NTH 512
#define NWAVES 8
#define KSLAB 256
#define NWIN 8
#define ETS 264                       /* etile stride in shorts */

typedef __attribute__((ext_vector_type(8))) short short8;
typedef __attribute__((ext_vector_type(4))) float float4v;
typedef __attribute__((ext_vector_type(4))) unsigned int uint4v;
typedef __attribute__((ext_vector_type(2))) unsigned int uint2v;

static __device__ __forceinline__ short f2bf(float f) {
  uint32_t u = __builtin_bit_cast(uint32_t, f);
  u = (u + 0x7FFFu + ((u >> 16) & 1u)) >> 16;   // RNE
  return (short)u;
}
static __device__ __forceinline__ float bf2f(short s) {
  uint32_t u = ((uint32_t)(uint16_t)s) << 16;
  return __builtin_bit_cast(float, u);
}
static __device__ __forceinline__ uint32_t packbf(float lo, float hi) {
  return ((uint32_t)(uint16_t)f2bf(hi) << 16) | (uint16_t)f2bf(lo);
}
static __device__ __forceinline__ uint32_t nz4(uint32_t d) {
  uint32_t x = (d & 0x7F7F7F7Fu) + 0x7F7F7F7Fu;
  x = (x | d) & 0x80808080u;
  return x >> 7;
}
static __device__ __forceinline__ uint32_t nib(uint32_t d) {
  return ((nz4(d) * 0x01020408u) >> 24) & 0xFu;
}

// dynamic LDS layout (bytes)
#define ETILE_BYTES (NWAVES * 16 * ETS * 2)        // 67584
#define MBITS_OFF   ETILE_BYTES
#define CBUF_OFF    (MBITS_OFF + QBLK * 65 * 4)    // 71744
#define LSUM_OFF    (CBUF_OFF + QBLK * 65 * 4)     // 75904
#define LINV_OFF    (LSUM_OFF + 64)
#define SMEM_BYTES  (LINV_OFF + 64)                // 76032 -> 2 blocks/CU

#define KBF_OFF    ((size_t)64)
#define KBF_BYTES  ((size_t)B_ * H_ * S_ * D_ * 2)
#define VT_OFF     (KBF_OFF + KBF_BYTES)
#define VT_BYTES   ((size_t)B_ * H_ * S_ * D_ * 2)

__global__ void detect_mask_dtype(const uint8_t* __restrict__ m, uint32_t* flag) {
  uint32_t a = 0, b = 0;
  for (int i = threadIdx.x; i < 65536; i += 256) {
    uint8_t x = m[i];
    if (i & 3) a |= x; else b |= x;
  }
  uint32_t bits = (a ? 1u : 0u) | (b ? 2u : 0u);
  if (bits) atomicOr(flag, bits);
}

__global__ __launch_bounds__(256) void prep_k(const float* __restrict__ K,
                                              short* __restrict__ Kbf) {
  size_t base = ((size_t)blockIdx.x * 256 + threadIdx.x) * 8;
  float4v a = __builtin_nontemporal_load((const float4v*)(K + base));
  float4v b = __builtin_nontemporal_load((const float4v*)(K + base + 4));
  short8 o;
  o[0]=f2bf(a.x); o[1]=f2bf(a.y); o[2]=f2bf(a.z); o[3]=f2bf(a.w);
  o[4]=f2bf(b.x); o[5]=f2bf(b.y); o[6]=f2bf(b.z); o[7]=f2bf(b.w);
  *(short8*)(Kbf + base) = o;
}

__global__ __launch_bounds__(256) void prep_vt(const float* __restrict__ V,
                                               short* __restrict__ VT) {
  __shared__ short tile[64][72];
  int bh = blockIdx.x >> 5, k0 = (blockIdx.x & 31) * 64;
  const float* src = V + ((size_t)bh * S_ + k0) * D_;
  int t = threadIdx.x;
  int r = t >> 2, c0 = (t & 3) * 16;
#pragma unroll
  for (int j = 0; j < 4; ++j) {
    float4v f = __builtin_nontemporal_load((const float4v*)(src + (size_t)r * D_ + c0 + j * 4));
    tile[r][c0 + j*4 + 0] = f2bf(f.x);
    tile[r][c0 + j*4 + 1] = f2bf(f.y);
    tile[r][c0 + j*4 + 2] = f2bf(f.z);
    tile[r][c0 + j*4 + 3] = f2bf(f.w);
  }
  __syncthreads();
  int d = t >> 2, ks0 = (t & 3) * 16;
  short* dst = VT + (size_t)bh * D_ * S_ + (size_t)d * S_ + k0 + ks0;
#pragma unroll
  for (int half = 0; half < 2; ++half) {
    short8 o;
#pragma unroll
    for (int i = 0; i < 8; ++i) o[i] = tile[ks0 + half * 8 + i][d];
    *(short8*)(dst + half * 8) = o;
  }
}

template <int PREP>
__global__ __launch_bounds__(NTH, 4) void attn_fused(
    const float* __restrict__ Q, const float* __restrict__ K,
    const float* __restrict__ V, const float* __restrict__ scale_p,
    const uint8_t* __restrict__ M, const uint32_t* __restrict__ flag,
    const short* __restrict__ Kbf, const short* __restrict__ VT,
    float* __restrict__ outC, float* __restrict__ outA)
{
  extern __shared__ char smem[];
  short*    etileA = (short*)smem;                      // [NWAVES][16][ETS]
  uint32_t* mbits  = (uint32_t*)(smem + MBITS_OFF);     // [QBLK][65]
  float*    cbuf   = (float*)(smem + CBUF_OFF);         // [QBLK][65]
  float*    lsum   = (float*)(smem + LSUM_OFF);
  float*    linv   = (float*)(smem + LINV_OFF);

  const int bx  = (blockIdx.x & 7) * 1024 + (blockIdx.x >> 3);
  const int bh  = bx >> 7;
  const int q0  = (bx & 127) * QBLK;

  const int tid  = threadIdx.x;
  const int w    = tid >> 6;
  const int lane = tid & 63;
  const int g    = lane >> 4;
  const int c    = lane & 15;
  const int kslab0 = w * KSLAB;

  const float scale = scale_p[0];
  const uint32_t fl = flag[0];

  const float* Qp  = Q + (size_t)bh * S_ * D_;
  const short* Kbp = Kbf + (size_t)bh * S_ * D_;
  const short* VTp = VT + (size_t)bh * D_ * S_;
  const float* Kfp = K + (size_t)bh * S_ * D_;
  const float* Vfp = V + (size_t)bh * S_ * D_;
  short* etile = etileA + w * 16 * ETS;

  // ---- early global loads (overlap with mask prologue) ----
  short8 kf[2][4];
#define LOADK(BUF, WIN) do {                                                   \
    const short* kr0_ = Kbp + (size_t)(kslab0 + (WIN) * 32 + c) * D_ + g * 8;  \
    kf[BUF][0] = *(const short8*)kr0_;                                         \
    kf[BUF][1] = *(const short8*)(kr0_ + 32);                                  \
    const short* kr1_ = kr0_ + 16 * D_;                                        \
    kf[BUF][2] = *(const short8*)kr1_;                                         \
    kf[BUF][3] = *(const short8*)(kr1_ + 32);                                  \
  } while (0)

  float4v qa = *(const float4v*)(Qp + (size_t)(q0 + c) * D_ + g * 8);
  float4v qb = *(const float4v*)(Qp + (size_t)(q0 + c) * D_ + g * 8 + 4);
  float4v qc2 = *(const float4v*)(Qp + (size_t)(q0 + c) * D_ + 32 + g * 8);
  float4v qd = *(const float4v*)(Qp + (size_t)(q0 + c) * D_ + 32 + g * 8 + 4);
  if (PREP) LOADK(0, 0);

  // ---- mask bitmap prologue ----
  {
    const int row = tid >> 5;
    const int w0  = (tid & 31) * 2;
    if (fl == 3u) {
      const uint8_t* mrow = M + ((size_t)bh * S_ + q0 + row) * (size_t)S_ + w0 * 32;
#pragma unroll
      for (int j = 0; j < 2; ++j) {
        uint4v a = __builtin_nontemporal_load((const uint4v*)(mrow + j * 32));
        uint4v b = __builtin_nontemporal_load((const uint4v*)(mrow + j * 32 + 16));
        uint32_t bits = nib(a.x) | (nib(a.y) << 4) | (nib(a.z) << 8)  | (nib(a.w) << 12)
                      | (nib(b.x) << 16) | (nib(b.y) << 20) | (nib(b.z) << 24) | (nib(b.w) << 28);
        mbits[row * 65 + w0 + j] = bits;
      }
    } else {
      const uint32_t* mrow = (const uint32_t*)M + ((size_t)bh * S_ + q0 + row) * (size_t)S_ + w0 * 32;
#pragma unroll
      for (int j = 0; j < 2; ++j) {
        uint32_t bits = 0;
#pragma unroll
        for (int u = 0; u < 8; ++u) {
          uint4v wv = __builtin_nontemporal_load((const uint4v*)(mrow + j * 32 + u * 4));
          uint32_t nzb = (wv.x ? 1u : 0u) | (wv.y ? 2u : 0u) | (wv.z ? 4u : 0u) | (wv.w ? 8u : 0u);
          bits |= nzb << (u * 4);
        }
        mbits[row * 65 + w0 + j] = bits;
      }
    }
    for (int i = tid; i < QBLK * 65; i += NTH) cbuf[i] = 0.0f;
    if (tid < QBLK) lsum[tid] = 0.0f;
  }
  __syncthreads();

  // ---- Q as B-frag ----
  short8 qB[2];
  {
    short8 f;
    f[0]=f2bf(qa.x); f[1]=f2bf(qa.y); f[2]=f2bf(qa.z); f[3]=f2bf(qa.w);
    f[4]=f2bf(qb.x); f[5]=f2bf(qb.y); f[6]=f2bf(qb.z); f[7]=f2bf(qb.w);
    qB[0] = f;
    f[0]=f2bf(qc2.x); f[1]=f2bf(qc2.y); f[2]=f2bf(qc2.z); f[3]=f2bf(qc2.w);
    f[4]=f2bf(qd.x); f[5]=f2bf(qd.y); f[6]=f2bf(qd.z); f[7]=f2bf(qd.w);
    qB[1] = f;
  }

  const uint32_t* mrowp = &mbits[c * 65 + (kslab0 >> 5)];
  float rsv = 0.0f;
  float4v cacc[4];
#pragma unroll
  for (int nd = 0; nd < 4; ++nd) cacc[nd] = (float4v){0.f, 0.f, 0.f, 0.f};

  // ---- phase 1 ----
#pragma unroll
  for (int win = 0; win < NWIN; ++win) {
    const int cur = win & 1;
    const int kwin = kslab0 + win * 32;

    // V frags for current window (issued early)
    short8 vA[4];
    if (PREP) {
#pragma unroll
      for (int nd = 0; nd < 4; ++nd)
        vA[nd] = *(const short8*)&VTp[(size_t)(nd * 16 + c) * S_ + kwin + g * 8];
    }

    short8 a0, a1, a2, a3;
    if (PREP) {
      a0 = kf[cur][0]; a1 = kf[cur][1]; a2 = kf[cur][2]; a3 = kf[cur][3];
      if (win + 1 < NWIN) { if (cur == 0) LOADK(1, win + 1); else LOADK(0, win + 1); }
    } else {
      const float* kr = Kfp + (size_t)(kwin + c) * D_ + g * 8;
      const float* kr1 = kr + 16 * D_;
#pragma unroll
      for (int e = 0; e < 8; ++e) {
        a0[e] = f2bf(kr[e]);  a1[e] = f2bf(kr[32 + e]);
        a2[e] = f2bf(kr1[e]); a3[e] = f2bf(kr1[32 + e]);
      }
#pragma unroll
      for (int nd = 0; nd < 4; ++nd) {
        const float* vc = Vfp + (size_t)(kwin + g * 8) * D_ + nd * 16 + c;
#pragma unroll
        for (int e = 0; e < 8; ++e) vA[nd][e] = f2bf(vc[(size_t)e * D_]);
      }
    }

    float4v acc0 = (float4v){0.f,0.f,0.f,0.f};
    float4v acc1 = (float4v){0.f,0.f,0.f,0.f};
    acc0 = __builtin_amdgcn_mfma_f32_16x16x32_bf16(a0, qB[0], acc0, 0, 0, 0);
    acc0 = __builtin_amdgcn_mfma_f32_16x16x32_bf16(a1, qB[1], acc0, 0, 0, 0);
    acc1 = __builtin_amdgcn_mfma_f32_16x16x32_bf16(a2, qB[0], acc1, 0, 0, 0);
    acc1 = __builtin_amdgcn_mfma_f32_16x16x32_bf16(a3, qB[1], acc1, 0, 0, 0);

    // mask + exp (lane's q = c; k = kwin + nb*16 + 4g + r)
    const uint32_t mw = mrowp[win];
    float e0[4], e1[4];
#pragma unroll
    for (int r = 0; r < 4; ++r) {
      e0[r] = ((mw >> (4 * g + r)) & 1u)      ? 1.0f : __expf(acc0[r] * scale);
      e1[r] = ((mw >> (16 + 4 * g + r)) & 1u) ? 1.0f : __expf(acc1[r] * scale);
      rsv += e0[r] + e1[r];
    }
    // E -> wave-private LDS tile
    uint2v lo, hi2;
    lo.x  = packbf(e0[0], e0[1]);  lo.y  = packbf(e0[2], e0[3]);
    hi2.x = packbf(e1[0], e1[1]);  hi2.y = packbf(e1[2], e1[3]);
    *(uint2v*)&etile[c * ETS + win * 32 + 4 * g]      = lo;
    *(uint2v*)&etile[c * ETS + win * 32 + 16 + 4 * g] = hi2;

    // PV B-frag straight from the tile (wave-private; lgkmcnt orders it)
    const short8 bfrag = *(const short8*)&etile[c * ETS + win * 32 + g * 8];
    cacc[0] = __builtin_amdgcn_mfma_f32_16x16x32_bf16(vA[0], bfrag, cacc[0], 0, 0, 0);
    cacc[1] = __builtin_amdgcn_mfma_f32_16x16x32_bf16(vA[1], bfrag, cacc[1], 0, 0, 0);
    cacc[2] = __builtin_amdgcn_mfma_f32_16x16x32_bf16(vA[2], bfrag, cacc[2], 0, 0, 0);
    cacc[3] = __builtin_amdgcn_mfma_f32_16x16x32_bf16(vA[3], bfrag, cacc[3], 0, 0, 0);
  }
#undef LOADK

  // ---- reductions ----
  rsv += __shfl_xor(rsv, 16);
  rsv += __shfl_xor(rsv, 32);
  if (lane < 16) atomicAdd(&lsum[lane], rsv);
#pragma unroll
  for (int nd = 0; nd < 4; ++nd)
#pragma unroll
    for (int r = 0; r < 4; ++r)
      atomicAdd(&cbuf[c * 65 + nd * 16 + 4 * g + r], cacc[nd][r]);
  __syncthreads();

  if (tid < QBLK) linv[tid] = 1.0f / lsum[tid];
  __syncthreads();

  // ---- context write ----
  if (tid < QBLK * D_ / 4) {
    const int row = tid >> 4, d0 = (tid & 15) * 4;
    const float inv = linv[row];
    float4v cv;
    cv.x = cbuf[row * 65 + d0 + 0] * inv;
    cv.y = cbuf[row * 65 + d0 + 1] * inv;
    cv.z = cbuf[row * 65 + d0 + 2] * inv;
    cv.w = cbuf[row * 65 + d0 + 3] * inv;
    *(float4v*)&outC[((size_t)(bh * S_ + q0 + row)) * D_ + d0] = cv;
  }

  // ---- phase 2: full-line normalized attention stores ----
  float* arowbase = outA + ((size_t)(bh * S_ + q0)) * S_ + kslab0 + lane * 4;
#pragma unroll
  for (int r16 = 0; r16 < 16; ++r16) {
    const float inv = linv[r16];
    const uint2v ev = *(const uint2v*)&etile[r16 * ETS + lane * 4];
    float4v av;
    av.x = bf2f((short)(ev.x & 0xffff)) * inv;
    av.y = bf2f((short)(ev.x >> 16))    * inv;
    av.z = bf2f((short)(ev.y & 0xffff)) * inv;
    av.w = bf2f((short)(ev.y >> 16))    * inv;
    __builtin_nontemporal_store(av, (float4v*)(arowbase + (size_t)r16 * S_));
  }
}

extern "C" void kernel_launch(void* const* d_in, const int* in_sizes, int n_in,
                              void* d_out, int out_size, void* d_ws, size_t ws_size,
                              hipStream_t stream) {
  const float*   Q     = (const float*)d_in[0];
  const float*   K     = (const float*)d_in[1];
  const float*   V     = (const float*)d_in[2];
  const float*   scale = (const float*)d_in[3];
  const uint8_t* M     = (const uint8_t*)d_in[4];
  uint32_t* flag = (uint32_t*)d_ws;
  short* Kbf = (short*)((char*)d_ws + KBF_OFF);
  short* VT  = (short*)((char*)d_ws + VT_OFF);
  float* outC = (float*)d_out;
  float* outA = outC + (size_t)B_ * H_ * S_ * D_;

  hipMemsetAsync(flag, 0, 4, stream);
  detect_mask_dtype<<<dim3(1), dim3(256), 0, stream>>>(M, flag);

  const bool prep = ws_size >= VT_OFF + VT_BYTES;
  const int grid = B_ * H_ * (S_ / QBLK);
  if (prep) {
    prep_k<<<dim3((B_ * H_ * S_ * D_) / (256 * 8)), dim3(256), 0, stream>>>(K, Kbf);
    prep_vt<<<dim3(B_ * H_ * (S_ / 64)), dim3(256), 0, stream>>>(V, VT);
    hipFuncSetAttribute(reinterpret_cast<const void*>(attn_fused<1>),
                        hipFuncAttributeMaxDynamicSharedMemorySize, SMEM_BYTES);
    attn_fused<1><<<dim3(grid), dim3(NTH), SMEM_BYTES, stream>>>(
        Q, K, V, scale, M, flag, Kbf, VT, outC, outA);
  } else {
    hipFuncSetAttribute(reinterpret_cast<const void*>(attn_fused<0>),
                        hipFuncAttributeMaxDynamicSharedMemorySize, SMEM_BYTES);
    attn_fused<0><<<dim3(grid), dim3(NTH), SMEM_BYTES, stream>>>(
        Q, K, V, scale, M, flag, Kbf, VT, outC, outA);
  }
}